// Round 1
// baseline (278.473 us; speedup 1.0000x reference)
//
#include <hip/hip_runtime.h>

// EWMA scan z_t = lam*z_{t-1} + (1-lam)*x_t over [B,L,K], chunk-parallel with
// 128-step warm-up (error <= lam^129 * max|z| ~ 1e-3 << 1.7e-2 threshold).
// One wave per (batch, chunk); lane owns 4 contiguous channels (float4).
//
// R2: statically-named bufA/bufB + manual 2-stage software pipeline (R1's
// dynamic-indexed buf[2][U] was demoted to scratch: VGPR=24, WRITE 3x ideal).
// R3 fix: native ext_vector float4 (HIP_vector_type rejects
// __builtin_nontemporal_store).
// R4: CHUNK 128 -> 32. Previous config was grid-limited to 1 wave/SIMD
// (Occupancy 9%, VALUBusy 2.4%, HBM 35% of peak => latency-bound, not
// BW-bound). 4096 wave-tasks -> 4 blocks/CU -> 16 waves/CU. Warm re-reads
// (5x logical) are Infinity-Cache hits: input (128 MiB) L3-fits, and FETCH
// already showed exactly 1x input at 2x logical reads. WARM stays 128 so
// accuracy is untouched. t0 now needs a max(0,...) clamp for chunks 1..3;
// all tile counts stay even multiples of UNROLL (4/8/12/16/20).

#define LAM   0.95f
#define CHUNK 32
#define WARM  128
#define UNROLL 8

typedef float v4f __attribute__((ext_vector_type(4)));

constexpr int B  = 16;
constexpr int L  = 8192;
constexpr int K  = 256;
constexpr int G  = L / CHUNK;   // 256 chunks per batch
constexpr int S4 = K / 4;       // 64 float4 per time step

__global__ __launch_bounds__(256) void ewma_kernel(const float* __restrict__ x,
                                                   float* __restrict__ out) {
    const int gw   = (int)((blockIdx.x * 256u + threadIdx.x) >> 6);
    const int lane = threadIdx.x & 63;
    const int b    = gw >> 8;                      // gw / G (G==256)
    const int j    = gw & (G - 1);                 // gw % G
    const int s    = j * CHUNK;                    // stored-region start
    const int tw   = s - WARM;
    const int t0   = tw < 0 ? 0 : tw;              // scan start (warm-up, clamped)

    const long chanoff = (long)b * L * K + (long)lane * 4;
    const v4f* __restrict__ pin  = (const v4f*)(x   + chanoff) + (long)t0 * S4;
    v4f*       __restrict__ pout = (v4f*)      (out + chanoff) + (long)t0 * S4;

    const float c = 1.0f - LAM;
    v4f z = {0.f, 0.f, 0.f, 0.f};

    const int total      = (s + CHUNK) - t0;       // 32/64/96/128 (j<4) or 160
    const int tiles      = total / UNROLL;         // 4/8/12/16/20 — always even
    const int warm_tiles = (s - t0) / UNROLL;      // 0/4/8/12/16

    v4f bufA[UNROLL], bufB[UNROLL];                // static names, constant idx only

    auto load_tile = [&](v4f (&buf)[UNROLL], int t) {
        const v4f* __restrict__ p = pin + (long)t * UNROLL * S4;
        #pragma unroll
        for (int u = 0; u < UNROLL; ++u) buf[u] = p[(long)u * S4];
    };

    auto comp_tile = [&](v4f (&buf)[UNROLL], int t) {
        v4f* __restrict__ p = pout + (long)t * UNROLL * S4;
        const bool st = (t >= warm_tiles);         // wave-uniform
        #pragma unroll
        for (int u = 0; u < UNROLL; ++u) {
            const v4f xv = buf[u];
            z.x = fmaf(LAM, z.x, c * xv.x);
            z.y = fmaf(LAM, z.y, c * xv.y);
            z.z = fmaf(LAM, z.z, c * xv.z);
            z.w = fmaf(LAM, z.w, c * xv.w);
            if (st) __builtin_nontemporal_store(z, &p[(long)u * S4]);
        }
    };

    load_tile(bufA, 0);
    for (int t = 0; t < tiles; t += 2) {
        load_tile(bufB, t + 1);                    // prefetch odd tile
        comp_tile(bufA, t);                        // compute even tile
        if (t + 2 < tiles) load_tile(bufA, t + 2); // prefetch next even tile
        comp_tile(bufB, t + 1);                    // compute odd tile
    }
}

extern "C" void kernel_launch(void* const* d_in, const int* in_sizes, int n_in,
                              void* d_out, int out_size, void* d_ws, size_t ws_size,
                              hipStream_t stream) {
    const float* x = (const float*)d_in[0];
    float* out = (float*)d_out;

    const int total_waves = B * G;       // 4096 wave-tasks
    const int blocks = total_waves / 4;  // 1024 blocks x 256 threads (4 blocks/CU)
    hipLaunchKernelGGL(ewma_kernel, dim3(blocks), dim3(256), 0, stream, x, out);
}

// Round 2
// 249.563 us; speedup vs baseline: 1.1158x; 1.1158x over previous
//
#include <hip/hip_runtime.h>

// EWMA scan z_t = lam*z_{t-1} + (1-lam)*x_t over [B,L,K], chunk-parallel with
// 128-step warm-up (error <= lam^129 * max|z| ~ 1e-3 << 1.7e-2 threshold).
//
// R2: statically-named bufA/bufB + manual 2-stage software pipeline (dynamic
//     indexing demotes to scratch).
// R4 FAILED: CHUNK 128->32 raised occupancy 9->33% but FETCH 130->300 MB
//     (5x logical warm re-reads stopped being cache-absorbed) -> 95->130us.
// R5: keep CHUNK=128 (R0 was traffic-optimal: FETCH==1x input) and get the
//     same 16 waves/CU by splitting K instead: 4 waves per (b,chunk), each
//     wave owns 64 channels, 1 float/lane (256B/load, fully coalesced).
//     block == (b,j) -> warm-read neighbor is adjacent block (cache-local).
//     UNROLL 8->16 (scalar tiles are cheap: 16 VGPR/buffer) for 4KB/wave
//     in flight.

#define LAM   0.95f
#define CHUNK 128
#define WARM  128
#define UNROLL 16

constexpr int B  = 16;
constexpr int L  = 8192;
constexpr int K  = 256;
constexpr int G  = L / CHUNK;   // 64 chunks per batch
constexpr int KS = 4;           // K-split: 4 waves per (b,j), 64 channels each

__global__ __launch_bounds__(256) void ewma_kernel(const float* __restrict__ x,
                                                   float* __restrict__ out) {
    const int wib  = (int)(threadIdx.x >> 6);     // K-slice 0..3 within block
    const int lane = threadIdx.x & 63;
    const int j    = blockIdx.x & (G - 1);        // chunk index
    const int b    = blockIdx.x >> 6;             // batch
    const int s    = j * CHUNK;                   // stored-region start
    const int t0   = (j == 0) ? 0 : (s - WARM);   // scan start (warm-up)

    const long chan = (long)b * L * K + wib * 64 + lane;  // this lane's channel
    const float* __restrict__ pin  = x   + chan + (long)t0 * K;
    float*       __restrict__ pout = out + chan + (long)t0 * K;

    const float c = 1.0f - LAM;
    float z = 0.f;

    const int total      = (s + CHUNK) - t0;      // 128 (chunk 0) or 256
    const int tiles      = total / UNROLL;        // 8 or 16 — always even
    const int warm_tiles = (s - t0) / UNROLL;     // 0 or 8

    float bufA[UNROLL], bufB[UNROLL];             // static names, constant idx only

    auto load_tile = [&](float (&buf)[UNROLL], int t) {
        const float* __restrict__ p = pin + (long)t * UNROLL * K;
        #pragma unroll
        for (int u = 0; u < UNROLL; ++u) buf[u] = p[(long)u * K];
    };

    auto comp_tile = [&](float (&buf)[UNROLL], int t) {
        float* __restrict__ p = pout + (long)t * UNROLL * K;
        const bool st = (t >= warm_tiles);        // wave-uniform
        #pragma unroll
        for (int u = 0; u < UNROLL; ++u) {
            z = fmaf(LAM, z, c * buf[u]);
            if (st) __builtin_nontemporal_store(z, &p[(long)u * K]);
        }
    };

    load_tile(bufA, 0);
    for (int t = 0; t < tiles; t += 2) {
        load_tile(bufB, t + 1);                    // prefetch odd tile
        comp_tile(bufA, t);                        // compute even tile
        if (t + 2 < tiles) load_tile(bufA, t + 2); // prefetch next even tile
        comp_tile(bufB, t + 1);                    // compute odd tile
    }
}

extern "C" void kernel_launch(void* const* d_in, const int* in_sizes, int n_in,
                              void* d_out, int out_size, void* d_ws, size_t ws_size,
                              hipStream_t stream) {
    const float* x = (const float*)d_in[0];
    float* out = (float*)d_out;

    const int blocks = B * G;            // 1024 blocks (one per (b,chunk))
    hipLaunchKernelGGL(ewma_kernel, dim3(blocks), dim3(256), 0, stream, x, out);
}